// Round 12
// baseline (689.366 us; speedup 1.0000x reference)
//
#include <hip/hip_runtime.h>
#include <hip/hip_bf16.h>

#define TB 2
#define TT 2048
#define TD 256
#define TE 64
#define TF 512
#define TN 4096      // TB*TT
#define TCAP 128     // 2*TN/TE
#define NITER 8

typedef __attribute__((ext_vector_type(8))) short bf16x8;
typedef __attribute__((ext_vector_type(4))) float f32x4;

__device__ inline float sanitize(float v){
  if (v != v) return 0.0f;
  const float FMAX = 3.402823466e+38f;
  if (v >  FMAX) return  FMAX;
  if (v < -FMAX) return -FMAX;
  return v;
}

__device__ inline short f2bf(float f){
  union { __hip_bfloat16 h; short s; } u;
  u.h = __float2bfloat16(f);
  return u.s;
}

__device__ inline float bf2f(short s){
  union { float f; unsigned int u; } v;
  v.u = ((unsigned int)(unsigned short)s) << 16;
  return v.f;
}

__device__ inline float gelu_tanh(float x){
  float x3 = x*x*x;
  return 0.5f*x*(1.0f + tanhf(0.7978845608028654f*(x + 0.044715f*x3)));
}

// async global->LDS, 16B per lane; dest = wave-uniform base + lane*16
__device__ __forceinline__ void gload16(const void* g, void* l){
  __builtin_amdgcn_global_load_lds(
      (__attribute__((address_space(1))) void*)g,
      (__attribute__((address_space(3))) void*)l, 16, 0, 0);
}

// ---------------- setup kernels ----------------

__global__ void k_init(const float* __restrict__ xs, const float* __restrict__ cosp,
                       const float* __restrict__ sinp, float* __restrict__ xw,
                       float* __restrict__ xt){
  int idx = blockIdx.x*256 + threadIdx.x;          // over TN*TD
  if (idx >= TN*TD) return;
  int d = idx & (TD-1);
  int n = idx >> 8;
  int t = n & (TT-1);
  float xr = sanitize(xs[2*idx]), xi = sanitize(xs[2*idx+1]);
  xw[2*idx] = xr; xw[2*idx+1] = xi;
  float tr, ti;
  if (t == 0){ tr = xr; ti = xi; }
  else {
    float pr = sanitize(xs[2*(idx-TD)]), pi = sanitize(xs[2*(idx-TD)+1]);
    float c = cosp[d], s = sinp[d];
    tr = pr*c - pi*s;
    ti = pr*s + pi*c;
  }
  xt[2*idx] = tr; xt[2*idx+1] = ti;
}

__global__ __launch_bounds__(64) void k_gatebias(const float* __restrict__ xw,
                                                 const float* __restrict__ wg,
                                                 float* __restrict__ gb){
  __shared__ float mag[TD];
  int n = blockIdx.x, t = threadIdx.x;
  for (int d = t; d < TD; d += 64){
    float xr = xw[(size_t)n*TF + 2*d], xi = xw[(size_t)n*TF + 2*d + 1];
    mag[d] = sqrtf(xr*xr + xi*xi + 1e-8f);
  }
  __syncthreads();
  float acc = 0.f;
  for (int d = 0; d < TD; d++) acc += mag[d]*wg[d*TE + t];
  gb[(size_t)n*TE + t] = acc;
}

// cast+transpose weights: in f32 [e][k][n] -> out bf16 [e][n][k]
__global__ __launch_bounds__(256) void k_castw(const float* __restrict__ W, short* __restrict__ Wt){
  __shared__ float tile[64][68];
  int e = blockIdx.y;
  int kt = (blockIdx.x >> 3) * 64;
  int nt = (blockIdx.x & 7) * 64;
  int tid = threadIdx.x;
  {
    int row = tid >> 4;
    int c4 = (tid & 15) * 4;
    #pragma unroll
    for (int i = 0; i < 4; i++){
      int r = row + i*16;
      float4 v = *(const float4*)(W + ((size_t)e*TF + kt + r)*TF + nt + c4);
      *(float4*)&tile[r][c4] = v;
    }
  }
  __syncthreads();
  #pragma unroll
  for (int i = 0; i < 2; i++){
    int un = tid + i*256;
    int nrow = un >> 3;
    int k8 = (un & 7) * 8;
    bf16x8 o;
    #pragma unroll
    for (int j = 0; j < 8; j++) o[j] = f2bf(tile[k8+j][nrow]);
    *(bf16x8*)(Wt + ((size_t)e*TF + nt + nrow)*TF + kt + k8) = o;
  }
}

// combine 4 floats at column col (multiple of 4): o = xOld + clip(lr*(xt - sum ye))  [bf16 ye]
__device__ __forceinline__ void combine4(const float* __restrict__ xOld,
                                         const float* __restrict__ xt,
                                         const short* __restrict__ ye,
                                         int c, const int* __restrict__ lst,
                                         int nrow, int col, float* o){
  size_t off = (size_t)nrow*TF + col;
  float4 a = *(const float4*)(xOld + off);
  float p0=0.f, p1=0.f, p2=0.f, p3=0.f;
  for (int j = 0; j < c; j++){
    short4 v = *(const short4*)(ye + (size_t)lst[j]*TF + col);
    p0 += bf2f(v.x); p1 += bf2f(v.y); p2 += bf2f(v.z); p3 += bf2f(v.w);
  }
  float4 t = *(const float4*)(xt + off);
  float u;
  u = 0.05f*(t.x - p0); u = fminf(10.f, fmaxf(-10.f, u)); o[0] = a.x + u;
  u = 0.05f*(t.y - p1); u = fminf(10.f, fmaxf(-10.f, u)); o[1] = a.y + u;
  u = 0.05f*(t.z - p2); u = fminf(10.f, fmaxf(-10.f, u)); o[2] = a.z + u;
  u = 0.05f*(t.w - p3); u = fminf(10.f, fmaxf(-10.f, u)); o[3] = a.w + u;
}

// ---------------- combine: xNew = xOld + clip(lr*(xt - gather(ye))) ----------------
// 8 rows/block, 32 lanes/row, strided cols (lane-consecutive 8B gathers).

__global__ __launch_bounds__(256) void k_combine(
    const float* __restrict__ xOld, float* __restrict__ xNew,
    const float* __restrict__ xt, const short* __restrict__ ye,
    const int* __restrict__ cnt, const int* __restrict__ list)
{
  int tid = threadIdx.x;
  int tok = tid >> 5;
  int lane5 = tid & 31;
  int n = blockIdx.x*8 + tok;
  int c = cnt[n];
  const int* lst = list + n*64;
  #pragma unroll
  for (int s = 0; s < 4; s++){
    int col = 4*lane5 + 128*s;
    float o[4];
    combine4(xOld, xt, ye, c, lst, n, col, o);
    *(float4*)(xNew + (size_t)n*TF + col) = make_float4(o[0], o[1], o[2], o[3]);
  }
}

// ---------------- delay embed + router + bf16 cast (dense x_state input) ----------------

__global__ __launch_bounds__(256) void k_fuse2(
    const float* __restrict__ xcur, const float* __restrict__ g,
    const float* __restrict__ wr, const float* __restrict__ gb,
    short* __restrict__ xbf, float* __restrict__ scoresT)
{
  __shared__ float xeff[8][516];
  __shared__ float Bt[64][68];
  int tid = threadIdx.x;
  int tok = tid >> 5;            // 0..7
  int lane5 = tid & 31;
  int kq  = lane5 * 16;          // 16 consecutive floats
  int n   = blockIdx.x*8 + tok;
  int t   = n & (TT-1);
  size_t rowoff = (size_t)n*TF + kq;

  float eff[16];
  {
    const float4* a4 = (const float4*)(xcur + rowoff);
    #pragma unroll
    for (int j = 0; j < 4; j++){
      float4 v = a4[j];
      eff[4*j+0] = v.x; eff[4*j+1] = v.y; eff[4*j+2] = v.z; eff[4*j+3] = v.w;
    }
  }
  const int taus[4] = {1,2,3,5};
  int d0 = kq >> 1;
  #pragma unroll
  for (int i = 0; i < 4; i++){
    int tau = taus[i];
    if (t >= tau){
      const float4* b4 = (const float4*)(xcur + rowoff - (size_t)tau*TF);
      float nb[16];
      #pragma unroll
      for (int j = 0; j < 4; j++){
        float4 v = b4[j];
        nb[4*j+0] = v.x; nb[4*j+1] = v.y; nb[4*j+2] = v.z; nb[4*j+3] = v.w;
      }
      #pragma unroll
      for (int p = 0; p < 8; p++){
        float gr = g[2*(i*TD + d0 + p)];
        float gi = g[2*(i*TD + d0 + p) + 1];
        eff[2*p]   += nb[2*p]*gr - nb[2*p+1]*gi;
        eff[2*p+1] += nb[2*p]*gi + nb[2*p+1]*gr;
      }
    }
  }
  {
    bf16x8 o0, o1;
    #pragma unroll
    for (int q = 0; q < 8; q++){ o0[q] = f2bf(eff[q]); o1[q] = f2bf(eff[8+q]); }
    *(bf16x8*)(xbf + rowoff)     = o0;
    *(bf16x8*)(xbf + rowoff + 8) = o1;
    #pragma unroll
    for (int jj = 0; jj < 4; jj++){
      int j = (jj + lane5) & 3;
      *(float4*)&xeff[tok][kq + 4*j] =
        make_float4(eff[4*j], eff[4*j+1], eff[4*j+2], eff[4*j+3]);
    }
  }
  __syncthreads();

  // router: thread (tok, tx) computes experts {2tx, 2tx+1} for token n
  int tx = lane5;
  float acc0 = gb[(size_t)n*TE + 2*tx];
  float acc1 = gb[(size_t)n*TE + 2*tx + 1];
  int rB = tid >> 2, c16 = (tid & 3)*16;
  for (int kk = 0; kk < TF; kk += 64){
    #pragma unroll
    for (int jj = 0; jj < 4; jj++)
      *(float4*)&Bt[rB][c16 + 4*jj] = *(const float4*)(wr + (size_t)(kk+rB)*TE + c16 + 4*jj);
    __syncthreads();
    #pragma unroll
    for (int k = 0; k < 64; k++){
      float a = xeff[tok][kk + k];
      float2 b = *(const float2*)&Bt[k][2*tx];
      acc0 += a*b.x; acc1 += a*b.y;
    }
    __syncthreads();
  }
  float m = fmaxf(acc0, acc1);
  #pragma unroll
  for (int off = 1; off < 32; off <<= 1) m = fmaxf(m, __shfl_xor(m, off));
  float e0 = expf(acc0 - m), e1 = expf(acc1 - m);
  float s = e0 + e1;
  #pragma unroll
  for (int off = 1; off < 32; off <<= 1) s += __shfl_xor(s, off);
  float inv = 1.0f / s;
  scoresT[(size_t)(2*tx)*TN + n]     = e0*inv;
  scoresT[(size_t)(2*tx+1)*TN + n]   = e1*inv;
}

// per-expert exact top-128: registers + 3-round radix, parallel threshold find.
__global__ __launch_bounds__(1024) void k_topk2(const float* __restrict__ scoresT,
                                                int* __restrict__ topi, float* __restrict__ topv,
                                                int* __restrict__ cnt){
  int e = blockIdx.x;
  const float* sc = scoresT + (size_t)e*TN;
  __shared__ unsigned int hist[4096];
  __shared__ unsigned int chunkSum[64];
  __shared__ unsigned int s_prefix;
  __shared__ int s_k, s_cnt, s_min;
  int tid = threadIdx.x;
  if (tid < 64) cnt[e*64 + tid] = 0;
  unsigned int u[4];
  #pragma unroll
  for (int i = 0; i < 4; i++) u[i] = __float_as_uint(sc[tid + i*1024]);
  if (tid == 0){ s_prefix = 0u; s_k = TCAP; }

  const int shifts[3]  = {20, 8, 0};
  const int nbins[3]   = {4096, 4096, 256};
  const unsigned int pmasks[3] = {0u, 0xFFF00000u, 0xFFFFFF00u};
  for (int r = 0; r < 3; r++){
    int shift = shifts[r], nb = nbins[r];
    unsigned int bmask = (unsigned)nb - 1u;
    int logC = (nb == 4096) ? 6 : 2;     // bins per chunk: nb/64
    for (int i = tid; i < nb; i += 1024) hist[i] = 0u;
    if (tid < 64) chunkSum[tid] = 0u;
    __syncthreads();
    unsigned int pref = s_prefix;
    unsigned int pmask = pmasks[r];
    #pragma unroll
    for (int i = 0; i < 4; i++)
      if ((u[i] & pmask) == pref) atomicAdd(&hist[(u[i] >> shift) & bmask], 1u);
    __syncthreads();
    for (int b = tid; b < nb; b += 1024){
      unsigned int h = hist[b];
      if (h) atomicAdd(&chunkSum[b >> logC], h);
    }
    __syncthreads();
    if (tid < 64){
      int chunk = 63 - tid;                     // lane order = descending chunk
      unsigned int s = chunkSum[chunk];
      unsigned int scan = s;
      #pragma unroll
      for (int d = 1; d < 64; d <<= 1){
        unsigned int t = __shfl_up(scan, d);
        if (tid >= d) scan += t;
      }
      unsigned int excl = scan - s;
      int k = s_k;
      if (excl < (unsigned)k && scan >= (unsigned)k){
        int C = 1 << logC;
        unsigned int cum = excl;
        for (int b = C-1; b >= 0; b--){
          unsigned int h = hist[(chunk << logC) + b];
          cum += h;
          if (cum >= (unsigned)k){
            s_k = k - (int)(cum - h);
            s_prefix = pref | ((unsigned)((chunk << logC) + b) << shift);
            break;
          }
        }
      }
    }
    __syncthreads();
  }
  unsigned int thr = s_prefix;
  int need_eq = s_k;
  if (tid == 0) s_cnt = 0;
  __syncthreads();
  #pragma unroll
  for (int i = 0; i < 4; i++){
    if (u[i] > thr){
      int p = atomicAdd(&s_cnt, 1);
      topi[e*TCAP + p] = tid + i*1024;
      topv[e*TCAP + p] = __uint_as_float(u[i]);
    }
  }
  __syncthreads();
  int base = s_cnt;
  int last = -1;
  for (int i = 0; i < need_eq; i++){
    __syncthreads();
    if (tid == 0) s_min = TN;
    __syncthreads();
    #pragma unroll
    for (int j = 0; j < 4; j++){
      int n = tid + j*1024;
      if (u[j] == thr && n > last) atomicMin(&s_min, n);
    }
    __syncthreads();
    int nsel = s_min;
    if (tid == 0){ topi[e*TCAP + base + i] = nsel; topv[e*TCAP + base + i] = __uint_as_float(thr); }
    last = nsel;
  }
}

// ---- GEMMs: bf16 Wt [e][n][k], BK=64, gload_lds + involution swizzle + counted vmcnt ----

__global__ __launch_bounds__(256) void k_gemm1c(const short* __restrict__ xbf,
                                                const short* __restrict__ W1t,
                                                const int* __restrict__ topi,
                                                short* __restrict__ hbf,
                                                int* __restrict__ cnt,
                                                int* __restrict__ list){
  __shared__ __align__(16) short As[2][128*64];
  __shared__ __align__(16) short Bs[2][64*64];
  __shared__ int rows[128];
  int bid = blockIdx.x;
  int swz = (bid & 7)*64 + (bid >> 3);     // XCD-contiguous: one XCD = 8 consecutive experts
  int e = swz >> 3, n0 = (swz & 7)*64;
  int tid = threadIdx.x;
  if (tid < 128) rows[tid] = topi[e*TCAP + tid];
  __syncthreads();
  // piggyback: n0==0 blocks build token -> ye-row inverse index (cnt zeroed by k_topk2)
  if (n0 == 0 && tid < 128){
    int n = rows[tid];
    int slot = atomicAdd(&cnt[n], 1);
    list[n*64 + slot] = e*TCAP + tid;
  }
  int rsub = tid >> 3;                                // 0..31
  int cs = ((tid & 7) ^ (rsub & 7))*8;                // swizzled source chunk (shorts)
  const short* sA0 = xbf + (size_t)rows[rsub      ]*TF + cs;
  const short* sA1 = xbf + (size_t)rows[rsub +  32]*TF + cs;
  const short* sA2 = xbf + (size_t)rows[rsub +  64]*TF + cs;
  const short* sA3 = xbf + (size_t)rows[rsub +  96]*TF + cs;
  const short* sB0 = W1t + ((size_t)e*TF + n0 + rsub)*TF + cs;
  const short* sB1 = sB0 + (size_t)32*TF;

  int w = tid >> 6, l = tid & 63;
  int lr = l & 15, lh = l >> 4;
  int lx = lr & 7;
  int ar0 = (32*w + lr)*64;
  int ar1 = ar0 + 16*64;
  int p0 = (lh ^ lx)*8;            // kk=0 chunk pos (shorts)
  int p1 = ((4 + lh) ^ lx)*8;      // kk=1

  f32x4 acc[2][4];
  #pragma unroll
  for (int m = 0; m < 2; m++)
    #pragma unroll
    for (int j = 0; j < 4; j++)
      #pragma unroll
      for (int r = 0; r < 4; r++) acc[m][j][r] = 0.f;

  // prologue: stage step 0 into buf 0
  gload16(sA0, &As[0][        tid*8]);
  gload16(sA1, &As[0][2048 +  tid*8]);
  gload16(sA2, &As[0][4096 +  tid*8]);
  gload16(sA3, &As[0][6144 +  tid*8]);
  gload16(sB0, &Bs[0][        tid*8]);
  gload16(sB1, &Bs[0][2048 +  tid*8]);

  int cur = 0;
  for (int t = 0; t < 8; t++){
    if (t < 7){
      int kk = (t+1)*64;
      gload16(sA0 + kk, &As[cur^1][        tid*8]);
      gload16(sA1 + kk, &As[cur^1][2048 +  tid*8]);
      gload16(sA2 + kk, &As[cur^1][4096 +  tid*8]);
      gload16(sA3 + kk, &As[cur^1][6144 +  tid*8]);
      gload16(sB0 + kk, &Bs[cur^1][        tid*8]);
      gload16(sB1 + kk, &Bs[cur^1][2048 +  tid*8]);
      asm volatile("s_waitcnt vmcnt(6)" ::: "memory");
    } else {
      asm volatile("s_waitcnt vmcnt(0)" ::: "memory");
    }
    __builtin_amdgcn_sched_barrier(0);
    __builtin_amdgcn_s_barrier();          // current buffer loaded by ALL waves
    __builtin_amdgcn_sched_barrier(0);
    #pragma unroll
    for (int kk = 0; kk < 2; kk++){
      int pc = kk ? p1 : p0;
      bf16x8 a0 = *(const bf16x8*)&As[cur][ar0 + pc];
      bf16x8 a1 = *(const bf16x8*)&As[cur][ar1 + pc];
      #pragma unroll
      for (int j = 0; j < 4; j++){
        bf16x8 b = *(const bf16x8*)&Bs[cur][(16*j + lr)*64 + pc];
        acc[0][j] = __builtin_amdgcn_mfma_f32_16x16x32_bf16(a0, b, acc[0][j], 0, 0, 0);
        acc[1][j] = __builtin_amdgcn_mfma_f32_16x16x32_bf16(a1, b, acc[1][j], 0, 0, 0);
      }
    }
    __builtin_amdgcn_sched_barrier(0);
    __builtin_amdgcn_s_barrier();          // all waves done reading -> safe to overwrite
    cur ^= 1;
  }
  short* hdst = hbf + (size_t)e*TCAP*TF;
  #pragma unroll
  for (int m = 0; m < 2; m++)
    #pragma unroll
    for (int j = 0; j < 4; j++)
      #pragma unroll
      for (int r = 0; r < 4; r++){
        int row = 32*w + 16*m + lh*4 + r;
        int col = n0 + 16*j + lr;
        hdst[(size_t)row*TF + col] = f2bf(gelu_tanh(acc[m][j][r]));
      }
}

__global__ __launch_bounds__(256) void k_gemm2c(const short* __restrict__ hbf,
                                                const short* __restrict__ W2t,
                                                const int* __restrict__ topi,
                                                const float* __restrict__ topv,
                                                short* __restrict__ ye){
  __shared__ __align__(16) short As[2][128*64];
  __shared__ __align__(16) short Bs[2][64*64];
  __shared__ float tv[128];
  int bid = blockIdx.x;
  int swz = (bid & 7)*64 + (bid >> 3);
  int e = swz >> 3, n0 = (swz & 7)*64;
  int tid = threadIdx.x;
  if (tid < 128) tv[tid] = topv[e*TCAP + tid];
  __syncthreads();
  int rsub = tid >> 3;
  int cs = ((tid & 7) ^ (rsub & 7))*8;
  const short* sA0 = hbf + ((size_t)e*TCAP + rsub)*TF + cs;
  const short* sA1 = sA0 + (size_t)32*TF;
  const short* sA2 = sA0 + (size_t)64*TF;
  const short* sA3 = sA0 + (size_t)96*TF;
  const short* sB0 = W2t + ((size_t)e*TF + n0 + rsub)*TF + cs;
  const short* sB1 = sB0 + (size_t)32*TF;

  int w = tid >> 6, l = tid & 63;
  int lr = l & 15, lh = l >> 4;
  int lx = lr & 7;
  int ar0 = (32*w + lr)*64;
  int ar1 = ar0 + 16*64;
  int p0 = (lh ^ lx)*8;
  int p1 = ((4 + lh) ^ lx)*8;

  f32x4 acc[2][4];
  #pragma unroll
  for (int m = 0; m < 2; m++)
    #pragma unroll
    for (int j = 0; j < 4; j++)
      #pragma unroll
      for (int r = 0; r < 4; r++) acc[m][j][r] = 0.f;

  gload16(sA0, &As[0][        tid*8]);
  gload16(sA1, &As[0][2048 +  tid*8]);
  gload16(sA2, &As[0][4096 +  tid*8]);
  gload16(sA3, &As[0][6144 +  tid*8]);
  gload16(sB0, &Bs[0][        tid*8]);
  gload16(sB1, &Bs[0][2048 +  tid*8]);

  int cur = 0;
  for (int t = 0; t < 8; t++){
    if (t < 7){
      int kk = (t+1)*64;
      gload16(sA0 + kk, &As[cur^1][        tid*8]);
      gload16(sA1 + kk, &As[cur^1][2048 +  tid*8]);
      gload16(sA2 + kk, &As[cur^1][4096 +  tid*8]);
      gload16(sA3 + kk, &As[cur^1][6144 +  tid*8]);
      gload16(sB0 + kk, &Bs[cur^1][        tid*8]);
      gload16(sB1 + kk, &Bs[cur^1][2048 +  tid*8]);
      asm volatile("s_waitcnt vmcnt(6)" ::: "memory");
    } else {
      asm volatile("s_waitcnt vmcnt(0)" ::: "memory");
    }
    __builtin_amdgcn_sched_barrier(0);
    __builtin_amdgcn_s_barrier();
    __builtin_amdgcn_sched_barrier(0);
    #pragma unroll
    for (int kk = 0; kk < 2; kk++){
      int pc = kk ? p1 : p0;
      bf16x8 a0 = *(const bf16x8*)&As[cur][ar0 + pc];
      bf16x8 a1 = *(const bf16x8*)&As[cur][ar1 + pc];
      #pragma unroll
      for (int j = 0; j < 4; j++){
        bf16x8 b = *(const bf16x8*)&Bs[cur][(16*j + lr)*64 + pc];
        acc[0][j] = __builtin_amdgcn_mfma_f32_16x16x32_bf16(a0, b, acc[0][j], 0, 0, 0);
        acc[1][j] = __builtin_amdgcn_mfma_f32_16x16x32_bf16(a1, b, acc[1][j], 0, 0, 0);
      }
    }
    __builtin_amdgcn_sched_barrier(0);
    __builtin_amdgcn_s_barrier();
    cur ^= 1;
  }
  // dense bf16 ye write (scaled by gate value) — no atomics
  short* ydst = ye + (size_t)e*TCAP*TF;
  #pragma unroll
  for (int m = 0; m < 2; m++)
    #pragma unroll
    for (int j = 0; j < 4; j++)
      #pragma unroll
      for (int r = 0; r < 4; r++){
        int row = 32*w + 16*m + lh*4 + r;
        int col = n0 + 16*j + lr;
        ydst[(size_t)row*TF + col] = f2bf(acc[m][j][r] * tv[row]);
      }
}

extern "C" void kernel_launch(void* const* d_in, const int* in_sizes, int n_in,
                              void* d_out, int out_size, void* d_ws, size_t ws_size,
                              hipStream_t stream){
  (void)in_sizes; (void)n_in; (void)out_size; (void)ws_size;
  const float* x_stream = (const float*)d_in[0];
  const float* gains    = (const float*)d_in[1];
  const float* Wg       = (const float*)d_in[2];
  const float* Wr       = (const float*)d_in[3];
  const float* W1       = (const float*)d_in[4];
  const float* W2       = (const float*)d_in[5];
  const float* cosp     = (const float*)d_in[6];
  const float* sinp     = (const float*)d_in[7];

  size_t off = 0;
  char* base = (char*)d_ws;
  auto alloc = [&](size_t bytes) -> void* {
    void* p = base + off;
    off += (bytes + 255) & ~(size_t)255;
    return p;
  };
  float* X0      = (float*)alloc((size_t)TN*TF*4);   // x ping
  float* X1      = (float*)alloc((size_t)TN*TF*4);   // x pong
  float* x_targ  = (float*)alloc((size_t)TN*TF*4);
  short* xf_bf   = (short*)alloc((size_t)TN*TF*2);
  float* gateb   = (float*)alloc((size_t)TN*TE*4);
  float* scoresT = (float*)alloc((size_t)TE*TN*4);
  int*   topi    = (int*)  alloc((size_t)TE*TCAP*4);
  float* topv    = (float*)alloc((size_t)TE*TCAP*4);
  short* h_bf    = (short*)alloc((size_t)TE*TCAP*TF*2);
  short* ye      = (short*)alloc((size_t)TE*TCAP*TF*2);   // dense bf16 expert outputs (scaled)
  int*   cnt     = (int*)  alloc((size_t)TN*4);
  int*   list    = (int*)  alloc((size_t)TN*64*4);
  short* W1t     = (short*)alloc((size_t)TE*TF*TF*2);
  short* W2t     = (short*)alloc((size_t)TE*TF*TF*2);

  k_init<<<(TN*TD + 255)/256, 256, 0, stream>>>(x_stream, cosp, sinp, X0, x_targ);
  k_gatebias<<<TN, 64, 0, stream>>>(X0, Wg, gateb);
  k_castw<<<dim3(64, TE), 256, 0, stream>>>(W1, W1t);
  k_castw<<<dim3(64, TE), 256, 0, stream>>>(W2, W2t);

  float* cur = X0;   // x_state(0)
  float* nxt = X1;
  for (int it = 0; it < NITER; it++){
    if (it > 0){
      k_combine<<<TN/8, 256, 0, stream>>>(cur, nxt, x_targ, ye, cnt, list);
      float* tmp = cur; cur = nxt; nxt = tmp;
    }
    k_fuse2<<<TN/8, 256, 0, stream>>>(cur, gains, Wr, gateb, xf_bf, scoresT);
    k_topk2<<<TE, 1024, 0, stream>>>(scoresT, topi, topv, cnt);
    k_gemm1c<<<TF/64*TE, 256, 0, stream>>>(xf_bf, W1t, topi, h_bf, cnt, list);
    k_gemm2c<<<TF/64*TE, 256, 0, stream>>>(h_bf, W2t, topi, topv, ye);
  }
  // out = x_state(8) = update(x_state(7), pred(7))
  k_combine<<<TN/8, 256, 0, stream>>>(cur, (float*)d_out, x_targ, ye, cnt, list);
}

// Round 13
// 616.907 us; speedup vs baseline: 1.1175x; 1.1175x over previous
//
#include <hip/hip_runtime.h>
#include <hip/hip_bf16.h>

#define TB 2
#define TT 2048
#define TD 256
#define TE 64
#define TF 512
#define TN 4096      // TB*TT
#define TCAP 128     // 2*TN/TE
#define NITER 8

typedef __attribute__((ext_vector_type(8))) short bf16x8;
typedef __attribute__((ext_vector_type(4))) float f32x4;

__device__ inline float sanitize(float v){
  if (v != v) return 0.0f;
  const float FMAX = 3.402823466e+38f;
  if (v >  FMAX) return  FMAX;
  if (v < -FMAX) return -FMAX;
  return v;
}

__device__ inline short f2bf(float f){
  union { __hip_bfloat16 h; short s; } u;
  u.h = __float2bfloat16(f);
  return u.s;
}

__device__ inline float bf2f(short s){
  union { float f; unsigned int u; } v;
  v.u = ((unsigned int)(unsigned short)s) << 16;
  return v.f;
}

__device__ inline float gelu_tanh(float x){
  float x3 = x*x*x;
  return 0.5f*x*(1.0f + tanhf(0.7978845608028654f*(x + 0.044715f*x3)));
}

// async global->LDS, 16B per lane; dest = wave-uniform base + lane*16
__device__ __forceinline__ void gload16(const void* g, void* l){
  __builtin_amdgcn_global_load_lds(
      (__attribute__((address_space(1))) void*)g,
      (__attribute__((address_space(3))) void*)l, 16, 0, 0);
}

// ---------------- setup kernels ----------------

__global__ void k_init(const float* __restrict__ xs, const float* __restrict__ cosp,
                       const float* __restrict__ sinp, float* __restrict__ xw,
                       float* __restrict__ xt){
  int idx = blockIdx.x*256 + threadIdx.x;          // over TN*TD
  if (idx >= TN*TD) return;
  int d = idx & (TD-1);
  int n = idx >> 8;
  int t = n & (TT-1);
  float xr = sanitize(xs[2*idx]), xi = sanitize(xs[2*idx+1]);
  xw[2*idx] = xr; xw[2*idx+1] = xi;
  float tr, ti;
  if (t == 0){ tr = xr; ti = xi; }
  else {
    float pr = sanitize(xs[2*(idx-TD)]), pi = sanitize(xs[2*(idx-TD)+1]);
    float c = cosp[d], s = sinp[d];
    tr = pr*c - pi*s;
    ti = pr*s + pi*c;
  }
  xt[2*idx] = tr; xt[2*idx+1] = ti;
}

__global__ __launch_bounds__(64) void k_gatebias(const float* __restrict__ xw,
                                                 const float* __restrict__ wg,
                                                 float* __restrict__ gb){
  __shared__ float mag[TD];
  int n = blockIdx.x, t = threadIdx.x;
  for (int d = t; d < TD; d += 64){
    float xr = xw[(size_t)n*TF + 2*d], xi = xw[(size_t)n*TF + 2*d + 1];
    mag[d] = sqrtf(xr*xr + xi*xi + 1e-8f);
  }
  __syncthreads();
  float acc = 0.f;
  for (int d = 0; d < TD; d++) acc += mag[d]*wg[d*TE + t];
  gb[(size_t)n*TE + t] = acc;
}

// cast+transpose weights: in f32 [e][k][n] -> out bf16 [e][n][k]
__global__ __launch_bounds__(256) void k_castw(const float* __restrict__ W, short* __restrict__ Wt){
  __shared__ float tile[64][68];
  int e = blockIdx.y;
  int kt = (blockIdx.x >> 3) * 64;
  int nt = (blockIdx.x & 7) * 64;
  int tid = threadIdx.x;
  {
    int row = tid >> 4;
    int c4 = (tid & 15) * 4;
    #pragma unroll
    for (int i = 0; i < 4; i++){
      int r = row + i*16;
      float4 v = *(const float4*)(W + ((size_t)e*TF + kt + r)*TF + nt + c4);
      *(float4*)&tile[r][c4] = v;
    }
  }
  __syncthreads();
  #pragma unroll
  for (int i = 0; i < 2; i++){
    int un = tid + i*256;
    int nrow = un >> 3;
    int k8 = (un & 7) * 8;
    bf16x8 o;
    #pragma unroll
    for (int j = 0; j < 8; j++) o[j] = f2bf(tile[k8+j][nrow]);
    *(bf16x8*)(Wt + ((size_t)e*TF + nt + nrow)*TF + kt + k8) = o;
  }
}

// ---------------- combine: xNew = xOld + clip(lr*(xt - gather(ye))) ----------------
// R10 structure: 8 rows/block, 32 lanes/row, kq = lane5*16 contiguous, ONE gather
// loop per thread (single dependent-load chain per list entry). bf16 ye.

__global__ __launch_bounds__(256) void k_combine(
    const float* __restrict__ xOld, float* __restrict__ xNew,
    const float* __restrict__ xt, const short* __restrict__ ye,
    const int* __restrict__ cnt, const int* __restrict__ list)
{
  int tid = threadIdx.x;
  int tok = tid >> 5;
  int lane5 = tid & 31;
  int kq = lane5 * 16;
  int n = blockIdx.x*8 + tok;
  size_t off = (size_t)n*TF + kq;
  float p[16];
  #pragma unroll
  for (int q = 0; q < 16; q++) p[q] = 0.f;
  int c = cnt[n];
  const int* lst = list + n*64;
  for (int j = 0; j < c; j++){
    const short* yrow = ye + (size_t)lst[j]*TF + kq;
    bf16x8 v0 = *(const bf16x8*)(yrow);
    bf16x8 v1 = *(const bf16x8*)(yrow + 8);
    #pragma unroll
    for (int q = 0; q < 8; q++){ p[q] += bf2f(v0[q]); p[8+q] += bf2f(v1[q]); }
  }
  const float4* a4 = (const float4*)(xOld + off);
  const float4* t4 = (const float4*)(xt + off);
  float4* o4 = (float4*)(xNew + off);
  #pragma unroll
  for (int j = 0; j < 4; j++){
    float4 a = a4[j], t = t4[j], o;
    float u;
    u = 0.05f*(t.x - p[4*j+0]); u = fminf(10.f, fmaxf(-10.f, u)); o.x = a.x + u;
    u = 0.05f*(t.y - p[4*j+1]); u = fminf(10.f, fmaxf(-10.f, u)); o.y = a.y + u;
    u = 0.05f*(t.z - p[4*j+2]); u = fminf(10.f, fmaxf(-10.f, u)); o.z = a.z + u;
    u = 0.05f*(t.w - p[4*j+3]); u = fminf(10.f, fmaxf(-10.f, u)); o.w = a.w + u;
    o4[j] = o;
  }
}

// ---------------- delay embed + router + bf16 cast (dense x_state input) ----------------

__global__ __launch_bounds__(256) void k_fuse2(
    const float* __restrict__ xcur, const float* __restrict__ g,
    const float* __restrict__ wr, const float* __restrict__ gb,
    short* __restrict__ xbf, float* __restrict__ scoresT)
{
  __shared__ float xeff[8][516];
  __shared__ float Bt[64][68];
  int tid = threadIdx.x;
  int tok = tid >> 5;            // 0..7
  int lane5 = tid & 31;
  int kq  = lane5 * 16;          // 16 consecutive floats
  int n   = blockIdx.x*8 + tok;
  int t   = n & (TT-1);
  size_t rowoff = (size_t)n*TF + kq;

  float eff[16];
  {
    const float4* a4 = (const float4*)(xcur + rowoff);
    #pragma unroll
    for (int j = 0; j < 4; j++){
      float4 v = a4[j];
      eff[4*j+0] = v.x; eff[4*j+1] = v.y; eff[4*j+2] = v.z; eff[4*j+3] = v.w;
    }
  }
  const int taus[4] = {1,2,3,5};
  int d0 = kq >> 1;
  #pragma unroll
  for (int i = 0; i < 4; i++){
    int tau = taus[i];
    if (t >= tau){
      const float4* b4 = (const float4*)(xcur + rowoff - (size_t)tau*TF);
      float nb[16];
      #pragma unroll
      for (int j = 0; j < 4; j++){
        float4 v = b4[j];
        nb[4*j+0] = v.x; nb[4*j+1] = v.y; nb[4*j+2] = v.z; nb[4*j+3] = v.w;
      }
      #pragma unroll
      for (int p = 0; p < 8; p++){
        float gr = g[2*(i*TD + d0 + p)];
        float gi = g[2*(i*TD + d0 + p) + 1];
        eff[2*p]   += nb[2*p]*gr - nb[2*p+1]*gi;
        eff[2*p+1] += nb[2*p]*gi + nb[2*p+1]*gr;
      }
    }
  }
  {
    bf16x8 o0, o1;
    #pragma unroll
    for (int q = 0; q < 8; q++){ o0[q] = f2bf(eff[q]); o1[q] = f2bf(eff[8+q]); }
    *(bf16x8*)(xbf + rowoff)     = o0;
    *(bf16x8*)(xbf + rowoff + 8) = o1;
    #pragma unroll
    for (int jj = 0; jj < 4; jj++){
      int j = (jj + lane5) & 3;
      *(float4*)&xeff[tok][kq + 4*j] =
        make_float4(eff[4*j], eff[4*j+1], eff[4*j+2], eff[4*j+3]);
    }
  }
  __syncthreads();

  // router: thread (tok, tx) computes experts {2tx, 2tx+1} for token n
  int tx = lane5;
  float acc0 = gb[(size_t)n*TE + 2*tx];
  float acc1 = gb[(size_t)n*TE + 2*tx + 1];
  int rB = tid >> 2, c16 = (tid & 3)*16;
  for (int kk = 0; kk < TF; kk += 64){
    #pragma unroll
    for (int jj = 0; jj < 4; jj++)
      *(float4*)&Bt[rB][c16 + 4*jj] = *(const float4*)(wr + (size_t)(kk+rB)*TE + c16 + 4*jj);
    __syncthreads();
    #pragma unroll
    for (int k = 0; k < 64; k++){
      float a = xeff[tok][kk + k];
      float2 b = *(const float2*)&Bt[k][2*tx];
      acc0 += a*b.x; acc1 += a*b.y;
    }
    __syncthreads();
  }
  float m = fmaxf(acc0, acc1);
  #pragma unroll
  for (int off = 1; off < 32; off <<= 1) m = fmaxf(m, __shfl_xor(m, off));
  float e0 = expf(acc0 - m), e1 = expf(acc1 - m);
  float s = e0 + e1;
  #pragma unroll
  for (int off = 1; off < 32; off <<= 1) s += __shfl_xor(s, off);
  float inv = 1.0f / s;
  scoresT[(size_t)(2*tx)*TN + n]     = e0*inv;
  scoresT[(size_t)(2*tx+1)*TN + n]   = e1*inv;
}

// per-expert exact top-128: registers + 3-round radix, parallel threshold find.
__global__ __launch_bounds__(1024) void k_topk2(const float* __restrict__ scoresT,
                                                int* __restrict__ topi, float* __restrict__ topv,
                                                int* __restrict__ cnt){
  int e = blockIdx.x;
  const float* sc = scoresT + (size_t)e*TN;
  __shared__ unsigned int hist[4096];
  __shared__ unsigned int chunkSum[64];
  __shared__ unsigned int s_prefix;
  __shared__ int s_k, s_cnt, s_min;
  int tid = threadIdx.x;
  if (tid < 64) cnt[e*64 + tid] = 0;
  unsigned int u[4];
  #pragma unroll
  for (int i = 0; i < 4; i++) u[i] = __float_as_uint(sc[tid + i*1024]);
  if (tid == 0){ s_prefix = 0u; s_k = TCAP; }

  const int shifts[3]  = {20, 8, 0};
  const int nbins[3]   = {4096, 4096, 256};
  const unsigned int pmasks[3] = {0u, 0xFFF00000u, 0xFFFFFF00u};
  for (int r = 0; r < 3; r++){
    int shift = shifts[r], nb = nbins[r];
    unsigned int bmask = (unsigned)nb - 1u;
    int logC = (nb == 4096) ? 6 : 2;     // bins per chunk: nb/64
    for (int i = tid; i < nb; i += 1024) hist[i] = 0u;
    if (tid < 64) chunkSum[tid] = 0u;
    __syncthreads();
    unsigned int pref = s_prefix;
    unsigned int pmask = pmasks[r];
    #pragma unroll
    for (int i = 0; i < 4; i++)
      if ((u[i] & pmask) == pref) atomicAdd(&hist[(u[i] >> shift) & bmask], 1u);
    __syncthreads();
    for (int b = tid; b < nb; b += 1024){
      unsigned int h = hist[b];
      if (h) atomicAdd(&chunkSum[b >> logC], h);
    }
    __syncthreads();
    if (tid < 64){
      int chunk = 63 - tid;                     // lane order = descending chunk
      unsigned int s = chunkSum[chunk];
      unsigned int scan = s;
      #pragma unroll
      for (int d = 1; d < 64; d <<= 1){
        unsigned int t = __shfl_up(scan, d);
        if (tid >= d) scan += t;
      }
      unsigned int excl = scan - s;
      int k = s_k;
      if (excl < (unsigned)k && scan >= (unsigned)k){
        int C = 1 << logC;
        unsigned int cum = excl;
        for (int b = C-1; b >= 0; b--){
          unsigned int h = hist[(chunk << logC) + b];
          cum += h;
          if (cum >= (unsigned)k){
            s_k = k - (int)(cum - h);
            s_prefix = pref | ((unsigned)((chunk << logC) + b) << shift);
            break;
          }
        }
      }
    }
    __syncthreads();
  }
  unsigned int thr = s_prefix;
  int need_eq = s_k;
  if (tid == 0) s_cnt = 0;
  __syncthreads();
  #pragma unroll
  for (int i = 0; i < 4; i++){
    if (u[i] > thr){
      int p = atomicAdd(&s_cnt, 1);
      topi[e*TCAP + p] = tid + i*1024;
      topv[e*TCAP + p] = __uint_as_float(u[i]);
    }
  }
  __syncthreads();
  int base = s_cnt;
  int last = -1;
  for (int i = 0; i < need_eq; i++){
    __syncthreads();
    if (tid == 0) s_min = TN;
    __syncthreads();
    #pragma unroll
    for (int j = 0; j < 4; j++){
      int n = tid + j*1024;
      if (u[j] == thr && n > last) atomicMin(&s_min, n);
    }
    __syncthreads();
    int nsel = s_min;
    if (tid == 0){ topi[e*TCAP + base + i] = nsel; topv[e*TCAP + base + i] = __uint_as_float(thr); }
    last = nsel;
  }
}

// ---- GEMMs: bf16 Wt [e][n][k], BK=64, gload_lds + involution swizzle + counted vmcnt ----

__global__ __launch_bounds__(256) void k_gemm1c(const short* __restrict__ xbf,
                                                const short* __restrict__ W1t,
                                                const int* __restrict__ topi,
                                                short* __restrict__ hbf,
                                                int* __restrict__ cnt,
                                                int* __restrict__ list){
  __shared__ __align__(16) short As[2][128*64];
  __shared__ __align__(16) short Bs[2][64*64];
  __shared__ int rows[128];
  int bid = blockIdx.x;
  int swz = (bid & 7)*64 + (bid >> 3);     // XCD-contiguous: one XCD = 8 consecutive experts
  int e = swz >> 3, n0 = (swz & 7)*64;
  int tid = threadIdx.x;
  if (tid < 128) rows[tid] = topi[e*TCAP + tid];
  __syncthreads();
  // piggyback: n0==0 blocks build token -> ye-row inverse index (cnt zeroed by k_topk2)
  if (n0 == 0 && tid < 128){
    int n = rows[tid];
    int slot = atomicAdd(&cnt[n], 1);
    list[n*64 + slot] = e*TCAP + tid;
  }
  int rsub = tid >> 3;                                // 0..31
  int cs = ((tid & 7) ^ (rsub & 7))*8;                // swizzled source chunk (shorts)
  const short* sA0 = xbf + (size_t)rows[rsub      ]*TF + cs;
  const short* sA1 = xbf + (size_t)rows[rsub +  32]*TF + cs;
  const short* sA2 = xbf + (size_t)rows[rsub +  64]*TF + cs;
  const short* sA3 = xbf + (size_t)rows[rsub +  96]*TF + cs;
  const short* sB0 = W1t + ((size_t)e*TF + n0 + rsub)*TF + cs;
  const short* sB1 = sB0 + (size_t)32*TF;

  int w = tid >> 6, l = tid & 63;
  int lr = l & 15, lh = l >> 4;
  int lx = lr & 7;
  int ar0 = (32*w + lr)*64;
  int ar1 = ar0 + 16*64;
  int p0 = (lh ^ lx)*8;            // kk=0 chunk pos (shorts)
  int p1 = ((4 + lh) ^ lx)*8;      // kk=1

  f32x4 acc[2][4];
  #pragma unroll
  for (int m = 0; m < 2; m++)
    #pragma unroll
    for (int j = 0; j < 4; j++)
      #pragma unroll
      for (int r = 0; r < 4; r++) acc[m][j][r] = 0.f;

  // prologue: stage step 0 into buf 0
  gload16(sA0, &As[0][        tid*8]);
  gload16(sA1, &As[0][2048 +  tid*8]);
  gload16(sA2, &As[0][4096 +  tid*8]);
  gload16(sA3, &As[0][6144 +  tid*8]);
  gload16(sB0, &Bs[0][        tid*8]);
  gload16(sB1, &Bs[0][2048 +  tid*8]);

  int cur = 0;
  for (int t = 0; t < 8; t++){
    if (t < 7){
      int kk = (t+1)*64;
      gload16(sA0 + kk, &As[cur^1][        tid*8]);
      gload16(sA1 + kk, &As[cur^1][2048 +  tid*8]);
      gload16(sA2 + kk, &As[cur^1][4096 +  tid*8]);
      gload16(sA3 + kk, &As[cur^1][6144 +  tid*8]);
      gload16(sB0 + kk, &Bs[cur^1][        tid*8]);
      gload16(sB1 + kk, &Bs[cur^1][2048 +  tid*8]);
      asm volatile("s_waitcnt vmcnt(6)" ::: "memory");
    } else {
      asm volatile("s_waitcnt vmcnt(0)" ::: "memory");
    }
    __builtin_amdgcn_sched_barrier(0);
    __builtin_amdgcn_s_barrier();          // current buffer loaded by ALL waves
    __builtin_amdgcn_sched_barrier(0);
    #pragma unroll
    for (int kk = 0; kk < 2; kk++){
      int pc = kk ? p1 : p0;
      bf16x8 a0 = *(const bf16x8*)&As[cur][ar0 + pc];
      bf16x8 a1 = *(const bf16x8*)&As[cur][ar1 + pc];
      #pragma unroll
      for (int j = 0; j < 4; j++){
        bf16x8 b = *(const bf16x8*)&Bs[cur][(16*j + lr)*64 + pc];
        acc[0][j] = __builtin_amdgcn_mfma_f32_16x16x32_bf16(a0, b, acc[0][j], 0, 0, 0);
        acc[1][j] = __builtin_amdgcn_mfma_f32_16x16x32_bf16(a1, b, acc[1][j], 0, 0, 0);
      }
    }
    __builtin_amdgcn_sched_barrier(0);
    __builtin_amdgcn_s_barrier();          // all waves done reading -> safe to overwrite
    cur ^= 1;
  }
  short* hdst = hbf + (size_t)e*TCAP*TF;
  #pragma unroll
  for (int m = 0; m < 2; m++)
    #pragma unroll
    for (int j = 0; j < 4; j++)
      #pragma unroll
      for (int r = 0; r < 4; r++){
        int row = 32*w + 16*m + lh*4 + r;
        int col = n0 + 16*j + lr;
        hdst[(size_t)row*TF + col] = f2bf(gelu_tanh(acc[m][j][r]));
      }
}

__global__ __launch_bounds__(256) void k_gemm2c(const short* __restrict__ hbf,
                                                const short* __restrict__ W2t,
                                                const int* __restrict__ topi,
                                                const float* __restrict__ topv,
                                                short* __restrict__ ye){
  __shared__ __align__(16) short As[2][128*64];
  __shared__ __align__(16) short Bs[2][64*64];
  __shared__ float tv[128];
  int bid = blockIdx.x;
  int swz = (bid & 7)*64 + (bid >> 3);
  int e = swz >> 3, n0 = (swz & 7)*64;
  int tid = threadIdx.x;
  if (tid < 128) tv[tid] = topv[e*TCAP + tid];
  __syncthreads();
  int rsub = tid >> 3;
  int cs = ((tid & 7) ^ (rsub & 7))*8;
  const short* sA0 = hbf + ((size_t)e*TCAP + rsub)*TF + cs;
  const short* sA1 = sA0 + (size_t)32*TF;
  const short* sA2 = sA0 + (size_t)64*TF;
  const short* sA3 = sA0 + (size_t)96*TF;
  const short* sB0 = W2t + ((size_t)e*TF + n0 + rsub)*TF + cs;
  const short* sB1 = sB0 + (size_t)32*TF;

  int w = tid >> 6, l = tid & 63;
  int lr = l & 15, lh = l >> 4;
  int lx = lr & 7;
  int ar0 = (32*w + lr)*64;
  int ar1 = ar0 + 16*64;
  int p0 = (lh ^ lx)*8;
  int p1 = ((4 + lh) ^ lx)*8;

  f32x4 acc[2][4];
  #pragma unroll
  for (int m = 0; m < 2; m++)
    #pragma unroll
    for (int j = 0; j < 4; j++)
      #pragma unroll
      for (int r = 0; r < 4; r++) acc[m][j][r] = 0.f;

  gload16(sA0, &As[0][        tid*8]);
  gload16(sA1, &As[0][2048 +  tid*8]);
  gload16(sA2, &As[0][4096 +  tid*8]);
  gload16(sA3, &As[0][6144 +  tid*8]);
  gload16(sB0, &Bs[0][        tid*8]);
  gload16(sB1, &Bs[0][2048 +  tid*8]);

  int cur = 0;
  for (int t = 0; t < 8; t++){
    if (t < 7){
      int kk = (t+1)*64;
      gload16(sA0 + kk, &As[cur^1][        tid*8]);
      gload16(sA1 + kk, &As[cur^1][2048 +  tid*8]);
      gload16(sA2 + kk, &As[cur^1][4096 +  tid*8]);
      gload16(sA3 + kk, &As[cur^1][6144 +  tid*8]);
      gload16(sB0 + kk, &Bs[cur^1][        tid*8]);
      gload16(sB1 + kk, &Bs[cur^1][2048 +  tid*8]);
      asm volatile("s_waitcnt vmcnt(6)" ::: "memory");
    } else {
      asm volatile("s_waitcnt vmcnt(0)" ::: "memory");
    }
    __builtin_amdgcn_sched_barrier(0);
    __builtin_amdgcn_s_barrier();
    __builtin_amdgcn_sched_barrier(0);
    #pragma unroll
    for (int kk = 0; kk < 2; kk++){
      int pc = kk ? p1 : p0;
      bf16x8 a0 = *(const bf16x8*)&As[cur][ar0 + pc];
      bf16x8 a1 = *(const bf16x8*)&As[cur][ar1 + pc];
      #pragma unroll
      for (int j = 0; j < 4; j++){
        bf16x8 b = *(const bf16x8*)&Bs[cur][(16*j + lr)*64 + pc];
        acc[0][j] = __builtin_amdgcn_mfma_f32_16x16x32_bf16(a0, b, acc[0][j], 0, 0, 0);
        acc[1][j] = __builtin_amdgcn_mfma_f32_16x16x32_bf16(a1, b, acc[1][j], 0, 0, 0);
      }
    }
    __builtin_amdgcn_sched_barrier(0);
    __builtin_amdgcn_s_barrier();
    cur ^= 1;
  }
  // dense bf16 ye write (scaled by gate value) — no atomics
  short* ydst = ye + (size_t)e*TCAP*TF;
  #pragma unroll
  for (int m = 0; m < 2; m++)
    #pragma unroll
    for (int j = 0; j < 4; j++)
      #pragma unroll
      for (int r = 0; r < 4; r++){
        int row = 32*w + 16*m + lh*4 + r;
        int col = n0 + 16*j + lr;
        ydst[(size_t)row*TF + col] = f2bf(acc[m][j][r] * tv[row]);
      }
}

extern "C" void kernel_launch(void* const* d_in, const int* in_sizes, int n_in,
                              void* d_out, int out_size, void* d_ws, size_t ws_size,
                              hipStream_t stream){
  (void)in_sizes; (void)n_in; (void)out_size; (void)ws_size;
  const float* x_stream = (const float*)d_in[0];
  const float* gains    = (const float*)d_in[1];
  const float* Wg       = (const float*)d_in[2];
  const float* Wr       = (const float*)d_in[3];
  const float* W1       = (const float*)d_in[4];
  const float* W2       = (const float*)d_in[5];
  const float* cosp     = (const float*)d_in[6];
  const float* sinp     = (const float*)d_in[7];

  size_t off = 0;
  char* base = (char*)d_ws;
  auto alloc = [&](size_t bytes) -> void* {
    void* p = base + off;
    off += (bytes + 255) & ~(size_t)255;
    return p;
  };
  float* X0      = (float*)alloc((size_t)TN*TF*4);   // x ping
  float* X1      = (float*)alloc((size_t)TN*TF*4);   // x pong
  float* x_targ  = (float*)alloc((size_t)TN*TF*4);
  short* xf_bf   = (short*)alloc((size_t)TN*TF*2);
  float* gateb   = (float*)alloc((size_t)TN*TE*4);
  float* scoresT = (float*)alloc((size_t)TE*TN*4);
  int*   topi    = (int*)  alloc((size_t)TE*TCAP*4);
  float* topv    = (float*)alloc((size_t)TE*TCAP*4);
  short* h_bf    = (short*)alloc((size_t)TE*TCAP*TF*2);
  short* ye      = (short*)alloc((size_t)TE*TCAP*TF*2);   // dense bf16 expert outputs (scaled)
  int*   cnt     = (int*)  alloc((size_t)TN*4);
  int*   list    = (int*)  alloc((size_t)TN*64*4);
  short* W1t     = (short*)alloc((size_t)TE*TF*TF*2);
  short* W2t     = (short*)alloc((size_t)TE*TF*TF*2);

  k_init<<<(TN*TD + 255)/256, 256, 0, stream>>>(x_stream, cosp, sinp, X0, x_targ);
  k_gatebias<<<TN, 64, 0, stream>>>(X0, Wg, gateb);
  k_castw<<<dim3(64, TE), 256, 0, stream>>>(W1, W1t);
  k_castw<<<dim3(64, TE), 256, 0, stream>>>(W2, W2t);

  float* cur = X0;   // x_state(0)
  float* nxt = X1;
  for (int it = 0; it < NITER; it++){
    if (it > 0){
      k_combine<<<TN/8, 256, 0, stream>>>(cur, nxt, x_targ, ye, cnt, list);
      float* tmp = cur; cur = nxt; nxt = tmp;
    }
    k_fuse2<<<TN/8, 256, 0, stream>>>(cur, gains, Wr, gateb, xf_bf, scoresT);
    k_topk2<<<TE, 1024, 0, stream>>>(scoresT, topi, topv, cnt);
    k_gemm1c<<<TF/64*TE, 256, 0, stream>>>(xf_bf, W1t, topi, h_bf, cnt, list);
    k_gemm2c<<<TF/64*TE, 256, 0, stream>>>(h_bf, W2t, topi, topv, ye);
  }
  // out = x_state(8) = update(x_state(7), pred(7))
  k_combine<<<TN/8, 256, 0, stream>>>(cur, (float*)d_out, x_targ, ye, cnt, list);
}

// Round 14
// 582.513 us; speedup vs baseline: 1.1834x; 1.0590x over previous
//
#include <hip/hip_runtime.h>
#include <hip/hip_bf16.h>

#define TB 2
#define TT 2048
#define TD 256
#define TE 64
#define TF 512
#define TN 4096      // TB*TT
#define TCAP 128     // 2*TN/TE
#define NITER 8

typedef __attribute__((ext_vector_type(8))) short bf16x8;
typedef __attribute__((ext_vector_type(4))) float f32x4;

__device__ inline float sanitize(float v){
  if (v != v) return 0.0f;
  const float FMAX = 3.402823466e+38f;
  if (v >  FMAX) return  FMAX;
  if (v < -FMAX) return -FMAX;
  return v;
}

__device__ inline short f2bf(float f){
  union { __hip_bfloat16 h; short s; } u;
  u.h = __float2bfloat16(f);
  return u.s;
}

__device__ inline float bf2f(short s){
  union { float f; unsigned int u; } v;
  v.u = ((unsigned int)(unsigned short)s) << 16;
  return v.f;
}

__device__ inline float gelu_tanh(float x){
  float x3 = x*x*x;
  return 0.5f*x*(1.0f + tanhf(0.7978845608028654f*(x + 0.044715f*x3)));
}

// async global->LDS, 16B per lane; dest = wave-uniform base + lane*16
__device__ __forceinline__ void gload16(const void* g, void* l){
  __builtin_amdgcn_global_load_lds(
      (__attribute__((address_space(1))) void*)g,
      (__attribute__((address_space(3))) void*)l, 16, 0, 0);
}

// ---------------- setup kernels ----------------

__global__ void k_init(const float* __restrict__ xs, const float* __restrict__ cosp,
                       const float* __restrict__ sinp, float* __restrict__ xw,
                       float* __restrict__ xt){
  int idx = blockIdx.x*256 + threadIdx.x;          // over TN*TD
  if (idx >= TN*TD) return;
  int d = idx & (TD-1);
  int n = idx >> 8;
  int t = n & (TT-1);
  float xr = sanitize(xs[2*idx]), xi = sanitize(xs[2*idx+1]);
  xw[2*idx] = xr; xw[2*idx+1] = xi;
  float tr, ti;
  if (t == 0){ tr = xr; ti = xi; }
  else {
    float pr = sanitize(xs[2*(idx-TD)]), pi = sanitize(xs[2*(idx-TD)+1]);
    float c = cosp[d], s = sinp[d];
    tr = pr*c - pi*s;
    ti = pr*s + pi*c;
  }
  xt[2*idx] = tr; xt[2*idx+1] = ti;
}

__global__ __launch_bounds__(64) void k_gatebias(const float* __restrict__ xw,
                                                 const float* __restrict__ wg,
                                                 float* __restrict__ gb){
  __shared__ float mag[TD];
  int n = blockIdx.x, t = threadIdx.x;
  for (int d = t; d < TD; d += 64){
    float xr = xw[(size_t)n*TF + 2*d], xi = xw[(size_t)n*TF + 2*d + 1];
    mag[d] = sqrtf(xr*xr + xi*xi + 1e-8f);
  }
  __syncthreads();
  float acc = 0.f;
  for (int d = 0; d < TD; d++) acc += mag[d]*wg[d*TE + t];
  gb[(size_t)n*TE + t] = acc;
}

// cast+transpose weights: in f32 [e][k][n] -> out bf16 [e][n][k]
__global__ __launch_bounds__(256) void k_castw(const float* __restrict__ W, short* __restrict__ Wt){
  __shared__ float tile[64][68];
  int e = blockIdx.y;
  int kt = (blockIdx.x >> 3) * 64;
  int nt = (blockIdx.x & 7) * 64;
  int tid = threadIdx.x;
  {
    int row = tid >> 4;
    int c4 = (tid & 15) * 4;
    #pragma unroll
    for (int i = 0; i < 4; i++){
      int r = row + i*16;
      float4 v = *(const float4*)(W + ((size_t)e*TF + kt + r)*TF + nt + c4);
      *(float4*)&tile[r][c4] = v;
    }
  }
  __syncthreads();
  #pragma unroll
  for (int i = 0; i < 2; i++){
    int un = tid + i*256;
    int nrow = un >> 3;
    int k8 = (un & 7) * 8;
    bf16x8 o;
    #pragma unroll
    for (int j = 0; j < 8; j++) o[j] = f2bf(tile[k8+j][nrow]);
    *(bf16x8*)(Wt + ((size_t)e*TF + nt + nrow)*TF + kt + k8) = o;
  }
}

// ---------------- combine: xNew = xOld + clip(lr*(xt - gather(ye))) ----------------
// 8 rows/block, 32 lanes/row, kq contiguous, ONE gather chain per thread. bf16 ye.

__global__ __launch_bounds__(256) void k_combine(
    const float* __restrict__ xOld, float* __restrict__ xNew,
    const float* __restrict__ xt, const short* __restrict__ ye,
    const int* __restrict__ cnt, const int* __restrict__ list)
{
  int tid = threadIdx.x;
  int tok = tid >> 5;
  int lane5 = tid & 31;
  int kq = lane5 * 16;
  int n = blockIdx.x*8 + tok;
  size_t off = (size_t)n*TF + kq;
  float p[16];
  #pragma unroll
  for (int q = 0; q < 16; q++) p[q] = 0.f;
  int c = cnt[n];
  const int* lst = list + n*64;
  for (int j = 0; j < c; j++){
    const short* yrow = ye + (size_t)lst[j]*TF + kq;
    bf16x8 v0 = *(const bf16x8*)(yrow);
    bf16x8 v1 = *(const bf16x8*)(yrow + 8);
    #pragma unroll
    for (int q = 0; q < 8; q++){ p[q] += bf2f(v0[q]); p[8+q] += bf2f(v1[q]); }
  }
  const float4* a4 = (const float4*)(xOld + off);
  const float4* t4 = (const float4*)(xt + off);
  float4* o4 = (float4*)(xNew + off);
  #pragma unroll
  for (int j = 0; j < 4; j++){
    float4 a = a4[j], t = t4[j], o;
    float u;
    u = 0.05f*(t.x - p[4*j+0]); u = fminf(10.f, fmaxf(-10.f, u)); o.x = a.x + u;
    u = 0.05f*(t.y - p[4*j+1]); u = fminf(10.f, fmaxf(-10.f, u)); o.y = a.y + u;
    u = 0.05f*(t.z - p[4*j+2]); u = fminf(10.f, fmaxf(-10.f, u)); o.z = a.z + u;
    u = 0.05f*(t.w - p[4*j+3]); u = fminf(10.f, fmaxf(-10.f, u)); o.w = a.w + u;
    o4[j] = o;
  }
}

// ---------------- delay embed + router + bf16 cast (dense x_state input) ----------------
// Router: thread (tok, half, tx16) owns experts 4*tx16..+3 over half of each 64-k tile.
// float4 Bt reads (4 experts) + float4 xeff reads (4 k) -> ~2.8x fewer LDS issues.

__global__ __launch_bounds__(256) void k_fuse2(
    const float* __restrict__ xcur, const float* __restrict__ g,
    const float* __restrict__ wr, const float* __restrict__ gb,
    short* __restrict__ xbf, float* __restrict__ scoresT)
{
  __shared__ float xeff[8][516];
  __shared__ float Bt[64][68];
  int tid = threadIdx.x;
  int tok = tid >> 5;            // 0..7
  int lane5 = tid & 31;
  int kq  = lane5 * 16;          // 16 consecutive floats
  int n   = blockIdx.x*8 + tok;
  int t   = n & (TT-1);
  size_t rowoff = (size_t)n*TF + kq;

  float eff[16];
  {
    const float4* a4 = (const float4*)(xcur + rowoff);
    #pragma unroll
    for (int j = 0; j < 4; j++){
      float4 v = a4[j];
      eff[4*j+0] = v.x; eff[4*j+1] = v.y; eff[4*j+2] = v.z; eff[4*j+3] = v.w;
    }
  }
  const int taus[4] = {1,2,3,5};
  int d0 = kq >> 1;
  #pragma unroll
  for (int i = 0; i < 4; i++){
    int tau = taus[i];
    if (t >= tau){
      const float4* b4 = (const float4*)(xcur + rowoff - (size_t)tau*TF);
      float nb[16];
      #pragma unroll
      for (int j = 0; j < 4; j++){
        float4 v = b4[j];
        nb[4*j+0] = v.x; nb[4*j+1] = v.y; nb[4*j+2] = v.z; nb[4*j+3] = v.w;
      }
      #pragma unroll
      for (int p = 0; p < 8; p++){
        float gr = g[2*(i*TD + d0 + p)];
        float gi = g[2*(i*TD + d0 + p) + 1];
        eff[2*p]   += nb[2*p]*gr - nb[2*p+1]*gi;
        eff[2*p+1] += nb[2*p]*gi + nb[2*p+1]*gr;
      }
    }
  }
  {
    bf16x8 o0, o1;
    #pragma unroll
    for (int q = 0; q < 8; q++){ o0[q] = f2bf(eff[q]); o1[q] = f2bf(eff[8+q]); }
    *(bf16x8*)(xbf + rowoff)     = o0;
    *(bf16x8*)(xbf + rowoff + 8) = o1;
    #pragma unroll
    for (int jj = 0; jj < 4; jj++){
      int j = (jj + lane5) & 3;
      *(float4*)&xeff[tok][kq + 4*j] =
        make_float4(eff[4*j], eff[4*j+1], eff[4*j+2], eff[4*j+3]);
    }
  }
  __syncthreads();

  // router
  int tx16 = lane5 & 15;
  int half = lane5 >> 4;
  float acc[4];
  if (half == 0){
    #pragma unroll
    for (int j = 0; j < 4; j++) acc[j] = gb[(size_t)n*TE + 4*tx16 + j];
  } else {
    #pragma unroll
    for (int j = 0; j < 4; j++) acc[j] = 0.f;
  }
  int rB = tid >> 2, c16 = (tid & 3)*16;
  for (int kt2 = 0; kt2 < TF; kt2 += 64){
    #pragma unroll
    for (int jj = 0; jj < 4; jj++)
      *(float4*)&Bt[rB][c16 + 4*jj] = *(const float4*)(wr + (size_t)(kt2+rB)*TE + c16 + 4*jj);
    __syncthreads();
    int kl0 = half*32;
    #pragma unroll
    for (int k4 = 0; k4 < 32; k4 += 4){
      float4 xv = *(const float4*)&xeff[tok][kt2 + kl0 + k4];
      #pragma unroll
      for (int i = 0; i < 4; i++){
        float4 b = *(const float4*)&Bt[kl0 + k4 + i][4*tx16];
        float xs = (i==0) ? xv.x : (i==1) ? xv.y : (i==2) ? xv.z : xv.w;
        acc[0] += xs*b.x; acc[1] += xs*b.y; acc[2] += xs*b.z; acc[3] += xs*b.w;
      }
    }
    __syncthreads();
  }
  // cross-half reduction: both halves end with the full-K sums
  #pragma unroll
  for (int j = 0; j < 4; j++) acc[j] += __shfl_xor(acc[j], 16);
  // softmax over 64 experts (16 tx16 x 4 experts, within each 16-lane half)
  float m = fmaxf(fmaxf(acc[0], acc[1]), fmaxf(acc[2], acc[3]));
  #pragma unroll
  for (int off = 1; off < 16; off <<= 1) m = fmaxf(m, __shfl_xor(m, off));
  float e0 = expf(acc[0]-m), e1 = expf(acc[1]-m), e2 = expf(acc[2]-m), e3 = expf(acc[3]-m);
  float s = e0+e1+e2+e3;
  #pragma unroll
  for (int off = 1; off < 16; off <<= 1) s += __shfl_xor(s, off);
  if (half == 0){
    float inv = 1.0f / s;
    scoresT[(size_t)(4*tx16+0)*TN + n] = e0*inv;
    scoresT[(size_t)(4*tx16+1)*TN + n] = e1*inv;
    scoresT[(size_t)(4*tx16+2)*TN + n] = e2*inv;
    scoresT[(size_t)(4*tx16+3)*TN + n] = e3*inv;
  }
}

// per-expert exact top-128: registers + 3-round radix, parallel threshold find.
__global__ __launch_bounds__(1024) void k_topk2(const float* __restrict__ scoresT,
                                                int* __restrict__ topi, float* __restrict__ topv,
                                                int* __restrict__ cnt){
  int e = blockIdx.x;
  const float* sc = scoresT + (size_t)e*TN;
  __shared__ unsigned int hist[4096];
  __shared__ unsigned int chunkSum[64];
  __shared__ unsigned int s_prefix;
  __shared__ int s_k, s_cnt, s_min;
  int tid = threadIdx.x;
  if (tid < 64) cnt[e*64 + tid] = 0;
  unsigned int u[4];
  #pragma unroll
  for (int i = 0; i < 4; i++) u[i] = __float_as_uint(sc[tid + i*1024]);
  if (tid == 0){ s_prefix = 0u; s_k = TCAP; }

  const int shifts[3]  = {20, 8, 0};
  const int nbins[3]   = {4096, 4096, 256};
  const unsigned int pmasks[3] = {0u, 0xFFF00000u, 0xFFFFFF00u};
  for (int r = 0; r < 3; r++){
    int shift = shifts[r], nb = nbins[r];
    unsigned int bmask = (unsigned)nb - 1u;
    int logC = (nb == 4096) ? 6 : 2;     // bins per chunk: nb/64
    for (int i = tid; i < nb; i += 1024) hist[i] = 0u;
    if (tid < 64) chunkSum[tid] = 0u;
    __syncthreads();
    unsigned int pref = s_prefix;
    unsigned int pmask = pmasks[r];
    #pragma unroll
    for (int i = 0; i < 4; i++)
      if ((u[i] & pmask) == pref) atomicAdd(&hist[(u[i] >> shift) & bmask], 1u);
    __syncthreads();
    for (int b = tid; b < nb; b += 1024){
      unsigned int h = hist[b];
      if (h) atomicAdd(&chunkSum[b >> logC], h);
    }
    __syncthreads();
    if (tid < 64){
      int chunk = 63 - tid;                     // lane order = descending chunk
      unsigned int s = chunkSum[chunk];
      unsigned int scan = s;
      #pragma unroll
      for (int d = 1; d < 64; d <<= 1){
        unsigned int t = __shfl_up(scan, d);
        if (tid >= d) scan += t;
      }
      unsigned int excl = scan - s;
      int k = s_k;
      if (excl < (unsigned)k && scan >= (unsigned)k){
        int C = 1 << logC;
        unsigned int cum = excl;
        for (int b = C-1; b >= 0; b--){
          unsigned int h = hist[(chunk << logC) + b];
          cum += h;
          if (cum >= (unsigned)k){
            s_k = k - (int)(cum - h);
            s_prefix = pref | ((unsigned)((chunk << logC) + b) << shift);
            break;
          }
        }
      }
    }
    __syncthreads();
  }
  unsigned int thr = s_prefix;
  int need_eq = s_k;
  if (tid == 0) s_cnt = 0;
  __syncthreads();
  #pragma unroll
  for (int i = 0; i < 4; i++){
    if (u[i] > thr){
      int p = atomicAdd(&s_cnt, 1);
      topi[e*TCAP + p] = tid + i*1024;
      topv[e*TCAP + p] = __uint_as_float(u[i]);
    }
  }
  __syncthreads();
  int base = s_cnt;
  int last = -1;
  for (int i = 0; i < need_eq; i++){
    __syncthreads();
    if (tid == 0) s_min = TN;
    __syncthreads();
    #pragma unroll
    for (int j = 0; j < 4; j++){
      int n = tid + j*1024;
      if (u[j] == thr && n > last) atomicMin(&s_min, n);
    }
    __syncthreads();
    int nsel = s_min;
    if (tid == 0){ topi[e*TCAP + base + i] = nsel; topv[e*TCAP + base + i] = __uint_as_float(thr); }
    last = nsel;
  }
}

// ---- GEMMs: bf16 Wt [e][n][k], BK=64, gload_lds + involution swizzle + counted vmcnt ----

__global__ __launch_bounds__(256) void k_gemm1c(const short* __restrict__ xbf,
                                                const short* __restrict__ W1t,
                                                const int* __restrict__ topi,
                                                short* __restrict__ hbf,
                                                int* __restrict__ cnt,
                                                int* __restrict__ list){
  __shared__ __align__(16) short As[2][128*64];
  __shared__ __align__(16) short Bs[2][64*64];
  __shared__ int rows[128];
  int bid = blockIdx.x;
  int swz = (bid & 7)*64 + (bid >> 3);     // XCD-contiguous: one XCD = 8 consecutive experts
  int e = swz >> 3, n0 = (swz & 7)*64;
  int tid = threadIdx.x;
  if (tid < 128) rows[tid] = topi[e*TCAP + tid];
  __syncthreads();
  // piggyback: n0==0 blocks build token -> ye-row inverse index (cnt zeroed by k_topk2)
  if (n0 == 0 && tid < 128){
    int n = rows[tid];
    int slot = atomicAdd(&cnt[n], 1);
    list[n*64 + slot] = e*TCAP + tid;
  }
  int rsub = tid >> 3;                                // 0..31
  int cs = ((tid & 7) ^ (rsub & 7))*8;                // swizzled source chunk (shorts)
  const short* sA0 = xbf + (size_t)rows[rsub      ]*TF + cs;
  const short* sA1 = xbf + (size_t)rows[rsub +  32]*TF + cs;
  const short* sA2 = xbf + (size_t)rows[rsub +  64]*TF + cs;
  const short* sA3 = xbf + (size_t)rows[rsub +  96]*TF + cs;
  const short* sB0 = W1t + ((size_t)e*TF + n0 + rsub)*TF + cs;
  const short* sB1 = sB0 + (size_t)32*TF;

  int w = tid >> 6, l = tid & 63;
  int lr = l & 15, lh = l >> 4;
  int lx = lr & 7;
  int ar0 = (32*w + lr)*64;
  int ar1 = ar0 + 16*64;
  int p0 = (lh ^ lx)*8;            // kk=0 chunk pos (shorts)
  int p1 = ((4 + lh) ^ lx)*8;      // kk=1

  f32x4 acc[2][4];
  #pragma unroll
  for (int m = 0; m < 2; m++)
    #pragma unroll
    for (int j = 0; j < 4; j++)
      #pragma unroll
      for (int r = 0; r < 4; r++) acc[m][j][r] = 0.f;

  // prologue: stage step 0 into buf 0
  gload16(sA0, &As[0][        tid*8]);
  gload16(sA1, &As[0][2048 +  tid*8]);
  gload16(sA2, &As[0][4096 +  tid*8]);
  gload16(sA3, &As[0][6144 +  tid*8]);
  gload16(sB0, &Bs[0][        tid*8]);
  gload16(sB1, &Bs[0][2048 +  tid*8]);

  int cur = 0;
  for (int t = 0; t < 8; t++){
    if (t < 7){
      int kk = (t+1)*64;
      gload16(sA0 + kk, &As[cur^1][        tid*8]);
      gload16(sA1 + kk, &As[cur^1][2048 +  tid*8]);
      gload16(sA2 + kk, &As[cur^1][4096 +  tid*8]);
      gload16(sA3 + kk, &As[cur^1][6144 +  tid*8]);
      gload16(sB0 + kk, &Bs[cur^1][        tid*8]);
      gload16(sB1 + kk, &Bs[cur^1][2048 +  tid*8]);
      asm volatile("s_waitcnt vmcnt(6)" ::: "memory");
    } else {
      asm volatile("s_waitcnt vmcnt(0)" ::: "memory");
    }
    __builtin_amdgcn_sched_barrier(0);
    __builtin_amdgcn_s_barrier();          // current buffer loaded by ALL waves
    __builtin_amdgcn_sched_barrier(0);
    #pragma unroll
    for (int kk = 0; kk < 2; kk++){
      int pc = kk ? p1 : p0;
      bf16x8 a0 = *(const bf16x8*)&As[cur][ar0 + pc];
      bf16x8 a1 = *(const bf16x8*)&As[cur][ar1 + pc];
      #pragma unroll
      for (int j = 0; j < 4; j++){
        bf16x8 b = *(const bf16x8*)&Bs[cur][(16*j + lr)*64 + pc];
        acc[0][j] = __builtin_amdgcn_mfma_f32_16x16x32_bf16(a0, b, acc[0][j], 0, 0, 0);
        acc[1][j] = __builtin_amdgcn_mfma_f32_16x16x32_bf16(a1, b, acc[1][j], 0, 0, 0);
      }
    }
    __builtin_amdgcn_sched_barrier(0);
    __builtin_amdgcn_s_barrier();          // all waves done reading -> safe to overwrite
    cur ^= 1;
  }
  short* hdst = hbf + (size_t)e*TCAP*TF;
  #pragma unroll
  for (int m = 0; m < 2; m++)
    #pragma unroll
    for (int j = 0; j < 4; j++)
      #pragma unroll
      for (int r = 0; r < 4; r++){
        int row = 32*w + 16*m + lh*4 + r;
        int col = n0 + 16*j + lr;
        hdst[(size_t)row*TF + col] = f2bf(gelu_tanh(acc[m][j][r]));
      }
}

__global__ __launch_bounds__(256) void k_gemm2c(const short* __restrict__ hbf,
                                                const short* __restrict__ W2t,
                                                const int* __restrict__ topi,
                                                const float* __restrict__ topv,
                                                short* __restrict__ ye){
  __shared__ __align__(16) short As[2][128*64];
  __shared__ __align__(16) short Bs[2][64*64];
  __shared__ float tv[128];
  int bid = blockIdx.x;
  int swz = (bid & 7)*64 + (bid >> 3);
  int e = swz >> 3, n0 = (swz & 7)*64;
  int tid = threadIdx.x;
  if (tid < 128) tv[tid] = topv[e*TCAP + tid];
  __syncthreads();
  int rsub = tid >> 3;
  int cs = ((tid & 7) ^ (rsub & 7))*8;
  const short* sA0 = hbf + ((size_t)e*TCAP + rsub)*TF + cs;
  const short* sA1 = sA0 + (size_t)32*TF;
  const short* sA2 = sA0 + (size_t)64*TF;
  const short* sA3 = sA0 + (size_t)96*TF;
  const short* sB0 = W2t + ((size_t)e*TF + n0 + rsub)*TF + cs;
  const short* sB1 = sB0 + (size_t)32*TF;

  int w = tid >> 6, l = tid & 63;
  int lr = l & 15, lh = l >> 4;
  int lx = lr & 7;
  int ar0 = (32*w + lr)*64;
  int ar1 = ar0 + 16*64;
  int p0 = (lh ^ lx)*8;
  int p1 = ((4 + lh) ^ lx)*8;

  f32x4 acc[2][4];
  #pragma unroll
  for (int m = 0; m < 2; m++)
    #pragma unroll
    for (int j = 0; j < 4; j++)
      #pragma unroll
      for (int r = 0; r < 4; r++) acc[m][j][r] = 0.f;

  gload16(sA0, &As[0][        tid*8]);
  gload16(sA1, &As[0][2048 +  tid*8]);
  gload16(sA2, &As[0][4096 +  tid*8]);
  gload16(sA3, &As[0][6144 +  tid*8]);
  gload16(sB0, &Bs[0][        tid*8]);
  gload16(sB1, &Bs[0][2048 +  tid*8]);

  int cur = 0;
  for (int t = 0; t < 8; t++){
    if (t < 7){
      int kk = (t+1)*64;
      gload16(sA0 + kk, &As[cur^1][        tid*8]);
      gload16(sA1 + kk, &As[cur^1][2048 +  tid*8]);
      gload16(sA2 + kk, &As[cur^1][4096 +  tid*8]);
      gload16(sA3 + kk, &As[cur^1][6144 +  tid*8]);
      gload16(sB0 + kk, &Bs[cur^1][        tid*8]);
      gload16(sB1 + kk, &Bs[cur^1][2048 +  tid*8]);
      asm volatile("s_waitcnt vmcnt(6)" ::: "memory");
    } else {
      asm volatile("s_waitcnt vmcnt(0)" ::: "memory");
    }
    __builtin_amdgcn_sched_barrier(0);
    __builtin_amdgcn_s_barrier();
    __builtin_amdgcn_sched_barrier(0);
    #pragma unroll
    for (int kk = 0; kk < 2; kk++){
      int pc = kk ? p1 : p0;
      bf16x8 a0 = *(const bf16x8*)&As[cur][ar0 + pc];
      bf16x8 a1 = *(const bf16x8*)&As[cur][ar1 + pc];
      #pragma unroll
      for (int j = 0; j < 4; j++){
        bf16x8 b = *(const bf16x8*)&Bs[cur][(16*j + lr)*64 + pc];
        acc[0][j] = __builtin_amdgcn_mfma_f32_16x16x32_bf16(a0, b, acc[0][j], 0, 0, 0);
        acc[1][j] = __builtin_amdgcn_mfma_f32_16x16x32_bf16(a1, b, acc[1][j], 0, 0, 0);
      }
    }
    __builtin_amdgcn_sched_barrier(0);
    __builtin_amdgcn_s_barrier();
    cur ^= 1;
  }
  // dense bf16 ye write (scaled by gate value) — no atomics
  short* ydst = ye + (size_t)e*TCAP*TF;
  #pragma unroll
  for (int m = 0; m < 2; m++)
    #pragma unroll
    for (int j = 0; j < 4; j++)
      #pragma unroll
      for (int r = 0; r < 4; r++){
        int row = 32*w + 16*m + lh*4 + r;
        int col = n0 + 16*j + lr;
        ydst[(size_t)row*TF + col] = f2bf(acc[m][j][r] * tv[row]);
      }
}

extern "C" void kernel_launch(void* const* d_in, const int* in_sizes, int n_in,
                              void* d_out, int out_size, void* d_ws, size_t ws_size,
                              hipStream_t stream){
  (void)in_sizes; (void)n_in; (void)out_size; (void)ws_size;
  const float* x_stream = (const float*)d_in[0];
  const float* gains    = (const float*)d_in[1];
  const float* Wg       = (const float*)d_in[2];
  const float* Wr       = (const float*)d_in[3];
  const float* W1       = (const float*)d_in[4];
  const float* W2       = (const float*)d_in[5];
  const float* cosp     = (const float*)d_in[6];
  const float* sinp     = (const float*)d_in[7];

  size_t off = 0;
  char* base = (char*)d_ws;
  auto alloc = [&](size_t bytes) -> void* {
    void* p = base + off;
    off += (bytes + 255) & ~(size_t)255;
    return p;
  };
  float* X0      = (float*)alloc((size_t)TN*TF*4);   // x ping
  float* X1      = (float*)alloc((size_t)TN*TF*4);   // x pong
  float* x_targ  = (float*)alloc((size_t)TN*TF*4);
  short* xf_bf   = (short*)alloc((size_t)TN*TF*2);
  float* gateb   = (float*)alloc((size_t)TN*TE*4);
  float* scoresT = (float*)alloc((size_t)TE*TN*4);
  int*   topi    = (int*)  alloc((size_t)TE*TCAP*4);
  float* topv    = (float*)alloc((size_t)TE*TCAP*4);
  short* h_bf    = (short*)alloc((size_t)TE*TCAP*TF*2);
  short* ye      = (short*)alloc((size_t)TE*TCAP*TF*2);   // dense bf16 expert outputs (scaled)
  int*   cnt     = (int*)  alloc((size_t)TN*4);
  int*   list    = (int*)  alloc((size_t)TN*64*4);
  short* W1t     = (short*)alloc((size_t)TE*TF*TF*2);
  short* W2t     = (short*)alloc((size_t)TE*TF*TF*2);

  k_init<<<(TN*TD + 255)/256, 256, 0, stream>>>(x_stream, cosp, sinp, X0, x_targ);
  k_gatebias<<<TN, 64, 0, stream>>>(X0, Wg, gateb);
  k_castw<<<dim3(64, TE), 256, 0, stream>>>(W1, W1t);
  k_castw<<<dim3(64, TE), 256, 0, stream>>>(W2, W2t);

  float* cur = X0;   // x_state(0)
  float* nxt = X1;
  for (int it = 0; it < NITER; it++){
    if (it > 0){
      k_combine<<<TN/8, 256, 0, stream>>>(cur, nxt, x_targ, ye, cnt, list);
      float* tmp = cur; cur = nxt; nxt = tmp;
    }
    k_fuse2<<<TN/8, 256, 0, stream>>>(cur, gains, Wr, gateb, xf_bf, scoresT);
    k_topk2<<<TE, 1024, 0, stream>>>(scoresT, topi, topv, cnt);
    k_gemm1c<<<TF/64*TE, 256, 0, stream>>>(xf_bf, W1t, topi, h_bf, cnt, list);
    k_gemm2c<<<TF/64*TE, 256, 0, stream>>>(h_bf, W2t, topi, topv, ye);
  }
  // out = x_state(8) = update(x_state(7), pred(7))
  k_combine<<<TN/8, 256, 0, stream>>>(cur, (float*)d_out, x_targ, ye, cnt, list);
}